// Round 10
// baseline (2178.440 us; speedup 1.0000x reference)
//
#include <hip/hip_runtime.h>
#include <hip/hip_bf16.h>
#include <stdint.h>

#define N_CELLS  512
#define N_PIX    25600
#define NBF      100      // n_bins_filter
#define MAXC     20
#define N_FRAMES 300
#define NBT      1500     // n_bins_total
#define N_INIT   100
#define T_STEPS  (NBT - N_INIT)   // 1400

#define RING   104        // logical ring (time mod RING)
#define RSTR   105        // LDS storage stride (odd -> conflict-free column writes)
#define NWG    64
#define CPW    (N_CELLS / NWG)    // 8 cells per WG
#define SCAN_THREADS (CPW * 64)   // 512
#define XDEPTH 8                  // exchange ring depth (producer lead <= ~2)

// ---------------- MFMA GEMM tiling ----------------
#define MT 64
#define NT 64
#define KT 32
#define KSPLIT 5
#define KCH (N_PIX / KSPLIT)      // 5120
#define APAD 8                    // LDS row pad (shorts)

typedef short    bf16x8 __attribute__((ext_vector_type(8)));
typedef float    f32x4  __attribute__((ext_vector_type(4)));
typedef unsigned short u16x4 __attribute__((ext_vector_type(4)));

// ============== MFMA GEMM partial: part[kb][t][c] = sum_{k in chunk} A[t,k]*B[c,k] ==============
// fp32 inputs converted to bf16 during LDS staging; fp32 MFMA accumulate.
__global__ __launch_bounds__(256) void gemm_mfma_k(
        const float* __restrict__ A,   // input_frames [300][25600]
        const float* __restrict__ B,   // spat_filters [512][25600]
        float* __restrict__ part)      // [KSPLIT][300][512]
{
    __shared__ __hip_bfloat16 As[MT][KT + APAD];
    __shared__ __hip_bfloat16 Bs[NT][KT + APAD];

    const int kb = blockIdx.x, tb = blockIdx.y, cb = blockIdx.z;
    const int tid  = threadIdx.x;
    const int wave = tid >> 6;          // 0..3 -> M sub-strip
    const int lane = tid & 63;
    const int t0 = tb * MT, c0 = cb * NT, k0 = kb * KCH;

    const int srow = tid >> 3;          // 0..31 (stage rows srow, srow+32)
    const int sk4  = (tid & 7) * 4;     // k offset 0,4,..,28

    f32x4 acc[4];
    #pragma unroll
    for (int n = 0; n < 4; ++n) acc[n] = (f32x4){0.f, 0.f, 0.f, 0.f};

    const int frow = wave * 16 + (lane & 15);   // fragment row within tile
    const int fk   = (lane >> 4) * 8;           // fragment k offset (0,8,16,24)

    for (int kc = 0; kc < KCH; kc += KT) {
        // ---- stage A,B (fp32 -> bf16) ----
        #pragma unroll
        for (int h = 0; h < 2; ++h) {
            const int r = srow + h * 32;
            float4 av = make_float4(0.f, 0.f, 0.f, 0.f);
            if (t0 + r < N_FRAMES)
                av = *(const float4*)&A[(size_t)(t0 + r) * N_PIX + k0 + kc + sk4];
            u16x4 ap;
            {
                __hip_bfloat16 b0 = __float2bfloat16(av.x), b1 = __float2bfloat16(av.y);
                __hip_bfloat16 b2 = __float2bfloat16(av.z), b3 = __float2bfloat16(av.w);
                ap[0] = *(unsigned short*)&b0; ap[1] = *(unsigned short*)&b1;
                ap[2] = *(unsigned short*)&b2; ap[3] = *(unsigned short*)&b3;
            }
            *(u16x4*)&As[r][sk4] = ap;
            const float4 bv = *(const float4*)&B[(size_t)(c0 + r) * N_PIX + k0 + kc + sk4];
            u16x4 bp;
            {
                __hip_bfloat16 b0 = __float2bfloat16(bv.x), b1 = __float2bfloat16(bv.y);
                __hip_bfloat16 b2 = __float2bfloat16(bv.z), b3 = __float2bfloat16(bv.w);
                bp[0] = *(unsigned short*)&b0; bp[1] = *(unsigned short*)&b1;
                bp[2] = *(unsigned short*)&b2; bp[3] = *(unsigned short*)&b3;
            }
            *(u16x4*)&Bs[r][sk4] = bp;
        }
        __syncthreads();

        // ---- fragments + 4 MFMA ----
        const bf16x8 af = *(const bf16x8*)&As[frow][fk];
        #pragma unroll
        for (int n = 0; n < 4; ++n) {
            const bf16x8 bf = *(const bf16x8*)&Bs[n * 16 + (lane & 15)][fk];
            acc[n] = __builtin_amdgcn_mfma_f32_16x16x32_bf16(af, bf, acc[n], 0, 0, 0);
        }
        __syncthreads();
    }

    // ---- epilogue: C mapping col=lane&15, row=(lane>>4)*4+reg ----
    #pragma unroll
    for (int n = 0; n < 4; ++n) {
        const int c = c0 + n * 16 + (lane & 15);
        #pragma unroll
        for (int r = 0; r < 4; ++r) {
            const int t = t0 + wave * 16 + (lane >> 4) * 4 + r;
            if (t < N_FRAMES)
                part[(size_t)kb * (N_FRAMES * N_CELLS) + (size_t)t * N_CELLS + c] = acc[n][r];
        }
    }
}

// ============== prep: fused reduce+stim + copy_init + X64 zero ==============
// stim[t][c] = bias[c] + sum_k fw[t,k] * (sum_kb part[kb][fs[t,k]][c])
__global__ __launch_bounds__(256) void prep_k(
        const float* __restrict__ part,   // [KSPLIT][300][512]
        const float* __restrict__ bias,   // [512]
        const float* __restrict__ fw,     // [1500][2]
        const int*   __restrict__ fs,     // [1500][2]
        const float* __restrict__ ini,    // [512][100]
        float* __restrict__ stimb,        // [1500][512]
        unsigned long long* __restrict__ X64,  // [XDEPTH*512]
        float* __restrict__ out)          // [512][1500]
{
    const int i = blockIdx.x * 256 + threadIdx.x;
    if (i < NBT * N_CELLS) {
        const int t = i >> 9, c = i & (N_CELLS - 1);
        const int t2 = t * 2;
        const int f0 = fs[t2], f1 = fs[t2 + 1];
        float s0 = 0.f, s1 = 0.f;
        #pragma unroll
        for (int kb = 0; kb < KSPLIT; ++kb) {
            s0 += part[(size_t)kb * (N_FRAMES * N_CELLS) + (size_t)f0 * N_CELLS + c];
            s1 += part[(size_t)kb * (N_FRAMES * N_CELLS) + (size_t)f1 * N_CELLS + c];
        }
        stimb[i] = bias[c] + fw[t2] * s0 + fw[t2 + 1] * s1;
    }
    if (i < N_CELLS * N_INIT) {
        const int c = i / N_INIT;
        const int j = i - c * N_INIT;
        out[(size_t)c * NBT + j] = ini[i];
    }
    if (i < XDEPTH * N_CELLS) X64[i] = 0ull;
}

__device__ __forceinline__ int wrap_slot(int t) {
    int s = t % RING;
    return (s < 0) ? s + RING : s;
}

// ============== persistent scan (R2, verbatim): 64 WGs, wave-per-cell, tagged-word exchange ==============
// Exchange word for step s: (uint64)(s+1) << 32 | f32_bits(spike).
__global__ __launch_bounds__(SCAN_THREADS) void scan_k(
        const float* __restrict__ stimb,  // [1500][512]
        const float* __restrict__ cf,     // [512][20][100]
        const float* __restrict__ ff,     // [512][100]
        const int*   __restrict__ sel,    // [512][20]
        const float* __restrict__ ini,    // [512][100]
        unsigned long long* __restrict__ X64,  // [XDEPTH][512] tagged exchange
        float* __restrict__ out)          // [512][1500]
{
    __shared__ __hip_bfloat16 win[N_CELLS][RSTR];   // spike-history ring, all cells
    __shared__ float newspike[N_CELLS];             // f32 spikes of time i-1
    __shared__ int   lag1src[CPW][32];
    __shared__ float lag1coef[CPW][32];

    const int wg   = blockIdx.x;
    const int tid  = threadIdx.x;
    const int wave = tid >> 6;
    const int lane = tid & 63;
    const int cell = wg * CPW + wave;

    // ---- per-lane static coefficients for the lag>=2 partial:
    //      lane -> lag lane+2 (c1v) and lag lane+66 (c2v, lane<=34) ----
    int   srcm[MAXC + 1];
    float c1v[MAXC + 1], c2v[MAXC + 1];
    #pragma unroll
    for (int m = 0; m <= MAXC; ++m) {
        const int s = (m < MAXC) ? sel[cell * MAXC + m] : cell;
        const float* f = (m < MAXC) ? (cf + (size_t)(cell * MAXC + m) * NBF)
                                    : (ff + (size_t)cell * NBF);
        srcm[m] = s;
        c1v[m]  = f[98 - lane];                        // lag lane+2 -> idx 98..35
        c2v[m]  = (lane <= 34) ? f[34 - lane] : 0.f;   // lag lane+66 -> idx 34..0
        if (lane == m) {                               // lag-1 tables (static index)
            lag1src[wave][m]  = s;
            lag1coef[wave][m] = f[NBF - 1];
        }
    }

    // ---- window init: zero ring, then initial spikes at times -100..-1 ----
    {
        __hip_bfloat16* wf = &win[0][0];
        for (int i = tid; i < N_CELLS * RSTR; i += SCAN_THREADS) wf[i] = __float2bfloat16(0.f);
        __syncthreads();
        for (int i = tid; i < N_CELLS * N_INIT; i += SCAN_THREADS) {
            const int c = i / N_INIT;
            const int b = i - c * N_INIT;
            win[c][wrap_slot(b - N_INIT)] = __float2bfloat16(ini[i]);
        }
    }
    __syncthreads();

    // slots for the partial (lags >=2) of the NEXT step to be computed:
    // pre-loop computes partial for step 0: lag lane+2 -> time -(lane+2)
    int slotp1 = wrap_slot(-2 - lane);
    int slotp2 = wrap_slot(-66 - lane);
    int slotw  = RING - 1;                 // slot(time i-1) used from i=1

    const float ini_last = ini[tid * N_INIT + (N_INIT - 1)];   // y_{-1}[tid]

    float stim_next = 0.f;
    if (lane == 0) stim_next = stimb[(size_t)(N_INIT - 1) * N_CELLS + cell];

    // partial_0 (lags 2..100 of step 0)
    float partial;
    {
        float p = 0.f;
        #pragma unroll
        for (int m = 0; m <= MAXC; ++m) {
            const float w1 = __bfloat162float(win[srcm[m]][slotp1]);
            const float w2 = __bfloat162float(win[srcm[m]][slotp2]);
            p = fmaf(w1, c1v[m], p);
            p = fmaf(w2, c2v[m], p);
        }
        #pragma unroll
        for (int off = 32; off > 0; off >>= 1) p += __shfl_xor(p, off, 64);
        partial = p;
    }

    for (int i = 0; i < T_STEPS; ++i) {
        // ---- 1. obtain y_{i-1}[tid] ----
        float val;
        if (i > 0) {
            const unsigned long long* wp = &X64[(size_t)((i - 1) & (XDEPTH - 1)) * N_CELLS + tid];
            unsigned long long w;
            do {
                w = __hip_atomic_load(wp, __ATOMIC_RELAXED, __HIP_MEMORY_SCOPE_AGENT);
            } while ((unsigned)(w >> 32) != (unsigned)i);
            val = __uint_as_float((unsigned)w);
        } else {
            val = ini_last;
        }

        // ---- 2. publish to LDS ----
        newspike[tid] = val;
        win[tid][slotw] = __float2bfloat16(val);
        __syncthreads();

        // ---- 3. critical lag-1 terms + sigmoid + post ----
        float term = 0.f;
        if (lane <= MAXC) {
            term = newspike[lag1src[wave][lane]] * lag1coef[wave][lane];
        }
        #pragma unroll
        for (int off = 16; off > 0; off >>= 1) term += __shfl_xor(term, off, 32);

        if (lane == 0) {
            const float g = stim_next + partial + term;
            const float s = 1.f / (1.f + __expf(-g));
            const unsigned long long pw =
                ((unsigned long long)(unsigned)(i + 1) << 32) |
                (unsigned long long)__float_as_uint(s);
            __hip_atomic_store(&X64[(size_t)(i & (XDEPTH - 1)) * N_CELLS + cell], pw,
                               __ATOMIC_RELAXED, __HIP_MEMORY_SCOPE_AGENT);
            out[(size_t)cell * NBT + N_INIT + i] = s;
        }

        // ---- 4. advance slots; compute partial for step i+1 (hidden under exchange) ----
        slotw  = (slotw  + 1 == RING) ? 0 : slotw  + 1;
        slotp1 = (slotp1 + 1 == RING) ? 0 : slotp1 + 1;
        slotp2 = (slotp2 + 1 == RING) ? 0 : slotp2 + 1;

        if (lane == 0 && i + 1 < T_STEPS)
            stim_next = stimb[(size_t)(N_INIT + i) * N_CELLS + cell];

        float p = 0.f;
        #pragma unroll
        for (int m = 0; m <= MAXC; ++m) {
            const float w1 = __bfloat162float(win[srcm[m]][slotp1]);
            const float w2 = __bfloat162float(win[srcm[m]][slotp2]);
            p = fmaf(w1, c1v[m], p);
            p = fmaf(w2, c2v[m], p);
        }
        #pragma unroll
        for (int off = 32; off > 0; off >>= 1) p += __shfl_xor(p, off, 64);
        partial = p;
    }
}

extern "C" void kernel_launch(void* const* d_in, const int* in_sizes, int n_in,
                              void* d_out, int out_size, void* d_ws, size_t ws_size,
                              hipStream_t stream) {
    const float* ini    = (const float*)d_in[0];   // initial_spikes [512][100]
    const float* frames = (const float*)d_in[1];   // input_frames  [300][25600]
    const float* sfil   = (const float*)d_in[2];   // spat_filters  [512][25600]
    const float* ff     = (const float*)d_in[3];   // feedback_filters [512][100]
    const float* cf     = (const float*)d_in[4];   // coupling_filters [512][20][100]
    const float* bias   = (const float*)d_in[5];   // [512][1]
    const float* fw     = (const float*)d_in[6];   // forward_weights [1500][2]
    const int*   sel    = (const int*)d_in[7];     // coupled_sel [512][20]
    const int*   fs     = (const int*)d_in[8];     // forward_sel [1500][2]
    float* out = (float*)d_out;
    float* ws  = (float*)d_ws;

    // ws layout (floats), non-overlapping:
    //   part  @ 0        (KSPLIT*153600 = 768000)
    //   stimb @ 768000   (768000)
    //   X64   @ 1536000  (XDEPTH*512 u64 = 8192 float-equiv)   total 1544192 floats
    float* part  = ws;
    float* stimb = ws + 768000;
    unsigned long long* X64 = (unsigned long long*)(ws + 1536000);

    hipLaunchKernelGGL(gemm_mfma_k,
                       dim3(KSPLIT, (N_FRAMES + MT - 1) / MT, N_CELLS / NT), dim3(256), 0, stream,
                       frames, sfil, part);
    hipLaunchKernelGGL(prep_k, dim3((NBT * N_CELLS + 255) / 256), dim3(256), 0, stream,
                       part, bias, fw, fs, ini, stimb, X64, out);
    hipLaunchKernelGGL(scan_k, dim3(NWG), dim3(SCAN_THREADS), 0, stream,
                       stimb, cf, ff, sel, ini, X64, out);
}

// Round 11
// 2078.432 us; speedup vs baseline: 1.0481x; 1.0481x over previous
//
#include <hip/hip_runtime.h>
#include <hip/hip_bf16.h>
#include <stdint.h>

#define N_CELLS  512
#define N_PIX    25600
#define NBF      100      // n_bins_filter
#define MAXC     20
#define N_FRAMES 300
#define NBT      1500     // n_bins_total
#define N_INIT   100
#define T_STEPS  (NBT - N_INIT)   // 1400

#define RING   104        // logical ring (time mod RING)
#define RSTR   105        // LDS storage stride (odd -> conflict-free column writes)
#define NWG    64
#define CPW    (N_CELLS / NWG)    // 8 cells per WG
#define SCAN_THREADS (CPW * 64)   // 512
#define XDEPTH 8                  // exchange ring depth (producer lead <= ~2)

// ---------------- MFMA GEMM tiling (R9 exact) ----------------
#define MT 64
#define NT 64
#define KT 32
#define KSPLIT 8
#define KCH (N_PIX / KSPLIT)      // 3200
#define APAD 8                    // LDS row pad (shorts)

typedef short    bf16x8 __attribute__((ext_vector_type(8)));
typedef float    f32x4  __attribute__((ext_vector_type(4)));
typedef unsigned short u16x4 __attribute__((ext_vector_type(4)));

// ============== MFMA GEMM partial: part[kb][t][c] = sum_{k in chunk} A[t,k]*B[c,k] ==============
// fp32 inputs converted to bf16 during LDS staging; fp32 MFMA accumulate.
__global__ __launch_bounds__(256) void gemm_mfma_k(
        const float* __restrict__ A,   // input_frames [300][25600]
        const float* __restrict__ B,   // spat_filters [512][25600]
        float* __restrict__ part)      // [KSPLIT][300][512]
{
    __shared__ __hip_bfloat16 As[MT][KT + APAD];
    __shared__ __hip_bfloat16 Bs[NT][KT + APAD];

    const int kb = blockIdx.x, tb = blockIdx.y, cb = blockIdx.z;
    const int tid  = threadIdx.x;
    const int wave = tid >> 6;          // 0..3 -> M sub-strip
    const int lane = tid & 63;
    const int t0 = tb * MT, c0 = cb * NT, k0 = kb * KCH;

    const int srow = tid >> 3;          // 0..31 (stage rows srow, srow+32)
    const int sk4  = (tid & 7) * 4;     // k offset 0,4,..,28

    f32x4 acc[4];
    #pragma unroll
    for (int n = 0; n < 4; ++n) acc[n] = (f32x4){0.f, 0.f, 0.f, 0.f};

    const int frow = wave * 16 + (lane & 15);   // fragment row within tile
    const int fk   = (lane >> 4) * 8;           // fragment k offset (0,8,16,24)

    for (int kc = 0; kc < KCH; kc += KT) {
        // ---- stage A,B (fp32 -> bf16) ----
        #pragma unroll
        for (int h = 0; h < 2; ++h) {
            const int r = srow + h * 32;
            float4 av = make_float4(0.f, 0.f, 0.f, 0.f);
            if (t0 + r < N_FRAMES)
                av = *(const float4*)&A[(size_t)(t0 + r) * N_PIX + k0 + kc + sk4];
            u16x4 ap;
            {
                __hip_bfloat16 b0 = __float2bfloat16(av.x), b1 = __float2bfloat16(av.y);
                __hip_bfloat16 b2 = __float2bfloat16(av.z), b3 = __float2bfloat16(av.w);
                ap[0] = *(unsigned short*)&b0; ap[1] = *(unsigned short*)&b1;
                ap[2] = *(unsigned short*)&b2; ap[3] = *(unsigned short*)&b3;
            }
            *(u16x4*)&As[r][sk4] = ap;
            const float4 bv = *(const float4*)&B[(size_t)(c0 + r) * N_PIX + k0 + kc + sk4];
            u16x4 bp;
            {
                __hip_bfloat16 b0 = __float2bfloat16(bv.x), b1 = __float2bfloat16(bv.y);
                __hip_bfloat16 b2 = __float2bfloat16(bv.z), b3 = __float2bfloat16(bv.w);
                bp[0] = *(unsigned short*)&b0; bp[1] = *(unsigned short*)&b1;
                bp[2] = *(unsigned short*)&b2; bp[3] = *(unsigned short*)&b3;
            }
            *(u16x4*)&Bs[r][sk4] = bp;
        }
        __syncthreads();

        // ---- fragments + 4 MFMA ----
        const bf16x8 af = *(const bf16x8*)&As[frow][fk];
        #pragma unroll
        for (int n = 0; n < 4; ++n) {
            const bf16x8 bf = *(const bf16x8*)&Bs[n * 16 + (lane & 15)][fk];
            acc[n] = __builtin_amdgcn_mfma_f32_16x16x32_bf16(af, bf, acc[n], 0, 0, 0);
        }
        __syncthreads();
    }

    // ---- epilogue: C mapping col=lane&15, row=(lane>>4)*4+reg ----
    #pragma unroll
    for (int n = 0; n < 4; ++n) {
        const int c = c0 + n * 16 + (lane & 15);
        #pragma unroll
        for (int r = 0; r < 4; ++r) {
            const int t = t0 + wave * 16 + (lane >> 4) * 4 + r;
            if (t < N_FRAMES)
                part[(size_t)kb * (N_FRAMES * N_CELLS) + (size_t)t * N_CELLS + c] = acc[n][r];
        }
    }
}

// ============== reduce split-K partials (R9 exact) ==============
__global__ void reduce_part_k(const float* __restrict__ part, float* __restrict__ spat) {
    int i = blockIdx.x * 256 + threadIdx.x;
    if (i < N_FRAMES * N_CELLS) {
        float s = 0.f;
        #pragma unroll
        for (int kb = 0; kb < KSPLIT; ++kb) s += part[(size_t)kb * (N_FRAMES * N_CELLS) + i];
        spat[i] = s;
    }
}

// ============== prep2: stim (from reduced spat) + copy_init + X64 zero ==============
__global__ __launch_bounds__(256) void prep2_k(
        const float* __restrict__ spat,   // [300][512]
        const float* __restrict__ bias,   // [512]
        const float* __restrict__ fw,     // [1500][2]
        const int*   __restrict__ fs,     // [1500][2]
        const float* __restrict__ ini,    // [512][100]
        float* __restrict__ stimb,        // [1500][512]
        unsigned long long* __restrict__ X64,  // [XDEPTH*512]
        float* __restrict__ out)          // [512][1500]
{
    const int i = blockIdx.x * 256 + threadIdx.x;
    if (i < NBT * N_CELLS) {
        const int t = i >> 9, c = i & (N_CELLS - 1);
        const int t2 = t * 2;
        float v = bias[c];
        v = fmaf(fw[t2],     spat[(size_t)fs[t2]     * N_CELLS + c], v);
        v = fmaf(fw[t2 + 1], spat[(size_t)fs[t2 + 1] * N_CELLS + c], v);
        stimb[i] = v;
    }
    if (i < N_CELLS * N_INIT) {
        const int c = i / N_INIT;
        const int j = i - c * N_INIT;
        out[(size_t)c * NBT + j] = ini[i];
    }
    if (i < XDEPTH * N_CELLS) X64[i] = 0ull;
}

__device__ __forceinline__ int wrap_slot(int t) {
    int s = t % RING;
    return (s < 0) ? s + RING : s;
}

// ============== persistent scan (R2/R9 verbatim): 64 WGs, wave-per-cell, tagged-word exchange ==============
// Exchange word for step s: (uint64)(s+1) << 32 | f32_bits(spike).
__global__ __launch_bounds__(SCAN_THREADS) void scan_k(
        const float* __restrict__ stimb,  // [1500][512]
        const float* __restrict__ cf,     // [512][20][100]
        const float* __restrict__ ff,     // [512][100]
        const int*   __restrict__ sel,    // [512][20]
        const float* __restrict__ ini,    // [512][100]
        unsigned long long* __restrict__ X64,  // [XDEPTH][512] tagged exchange
        float* __restrict__ out)          // [512][1500]
{
    __shared__ __hip_bfloat16 win[N_CELLS][RSTR];   // spike-history ring, all cells
    __shared__ float newspike[N_CELLS];             // f32 spikes of time i-1
    __shared__ int   lag1src[CPW][32];
    __shared__ float lag1coef[CPW][32];

    const int wg   = blockIdx.x;
    const int tid  = threadIdx.x;
    const int wave = tid >> 6;
    const int lane = tid & 63;
    const int cell = wg * CPW + wave;

    // ---- per-lane static coefficients for the lag>=2 partial:
    //      lane -> lag lane+2 (c1v) and lag lane+66 (c2v, lane<=34) ----
    int   srcm[MAXC + 1];
    float c1v[MAXC + 1], c2v[MAXC + 1];
    #pragma unroll
    for (int m = 0; m <= MAXC; ++m) {
        const int s = (m < MAXC) ? sel[cell * MAXC + m] : cell;
        const float* f = (m < MAXC) ? (cf + (size_t)(cell * MAXC + m) * NBF)
                                    : (ff + (size_t)cell * NBF);
        srcm[m] = s;
        c1v[m]  = f[98 - lane];                        // lag lane+2 -> idx 98..35
        c2v[m]  = (lane <= 34) ? f[34 - lane] : 0.f;   // lag lane+66 -> idx 34..0
        if (lane == m) {                               // lag-1 tables (static index)
            lag1src[wave][m]  = s;
            lag1coef[wave][m] = f[NBF - 1];
        }
    }

    // ---- window init: zero ring, then initial spikes at times -100..-1 ----
    {
        __hip_bfloat16* wf = &win[0][0];
        for (int i = tid; i < N_CELLS * RSTR; i += SCAN_THREADS) wf[i] = __float2bfloat16(0.f);
        __syncthreads();
        for (int i = tid; i < N_CELLS * N_INIT; i += SCAN_THREADS) {
            const int c = i / N_INIT;
            const int b = i - c * N_INIT;
            win[c][wrap_slot(b - N_INIT)] = __float2bfloat16(ini[i]);
        }
    }
    __syncthreads();

    // slots for the partial (lags >=2) of the NEXT step to be computed:
    // pre-loop computes partial for step 0: lag lane+2 -> time -(lane+2)
    int slotp1 = wrap_slot(-2 - lane);
    int slotp2 = wrap_slot(-66 - lane);
    int slotw  = RING - 1;                 // slot(time i-1) used from i=1

    const float ini_last = ini[tid * N_INIT + (N_INIT - 1)];   // y_{-1}[tid]

    float stim_next = 0.f;
    if (lane == 0) stim_next = stimb[(size_t)(N_INIT - 1) * N_CELLS + cell];

    // partial_0 (lags 2..100 of step 0)
    float partial;
    {
        float p = 0.f;
        #pragma unroll
        for (int m = 0; m <= MAXC; ++m) {
            const float w1 = __bfloat162float(win[srcm[m]][slotp1]);
            const float w2 = __bfloat162float(win[srcm[m]][slotp2]);
            p = fmaf(w1, c1v[m], p);
            p = fmaf(w2, c2v[m], p);
        }
        #pragma unroll
        for (int off = 32; off > 0; off >>= 1) p += __shfl_xor(p, off, 64);
        partial = p;
    }

    for (int i = 0; i < T_STEPS; ++i) {
        // ---- 1. obtain y_{i-1}[tid] ----
        float val;
        if (i > 0) {
            const unsigned long long* wp = &X64[(size_t)((i - 1) & (XDEPTH - 1)) * N_CELLS + tid];
            unsigned long long w;
            do {
                w = __hip_atomic_load(wp, __ATOMIC_RELAXED, __HIP_MEMORY_SCOPE_AGENT);
            } while ((unsigned)(w >> 32) != (unsigned)i);
            val = __uint_as_float((unsigned)w);
        } else {
            val = ini_last;
        }

        // ---- 2. publish to LDS ----
        newspike[tid] = val;
        win[tid][slotw] = __float2bfloat16(val);
        __syncthreads();

        // ---- 3. critical lag-1 terms + sigmoid + post ----
        float term = 0.f;
        if (lane <= MAXC) {
            term = newspike[lag1src[wave][lane]] * lag1coef[wave][lane];
        }
        #pragma unroll
        for (int off = 16; off > 0; off >>= 1) term += __shfl_xor(term, off, 32);

        if (lane == 0) {
            const float g = stim_next + partial + term;
            const float s = 1.f / (1.f + __expf(-g));
            const unsigned long long pw =
                ((unsigned long long)(unsigned)(i + 1) << 32) |
                (unsigned long long)__float_as_uint(s);
            __hip_atomic_store(&X64[(size_t)(i & (XDEPTH - 1)) * N_CELLS + cell], pw,
                               __ATOMIC_RELAXED, __HIP_MEMORY_SCOPE_AGENT);
            out[(size_t)cell * NBT + N_INIT + i] = s;
        }

        // ---- 4. advance slots; compute partial for step i+1 (hidden under exchange) ----
        slotw  = (slotw  + 1 == RING) ? 0 : slotw  + 1;
        slotp1 = (slotp1 + 1 == RING) ? 0 : slotp1 + 1;
        slotp2 = (slotp2 + 1 == RING) ? 0 : slotp2 + 1;

        if (lane == 0 && i + 1 < T_STEPS)
            stim_next = stimb[(size_t)(N_INIT + i) * N_CELLS + cell];

        float p = 0.f;
        #pragma unroll
        for (int m = 0; m <= MAXC; ++m) {
            const float w1 = __bfloat162float(win[srcm[m]][slotp1]);
            const float w2 = __bfloat162float(win[srcm[m]][slotp2]);
            p = fmaf(w1, c1v[m], p);
            p = fmaf(w2, c2v[m], p);
        }
        #pragma unroll
        for (int off = 32; off > 0; off >>= 1) p += __shfl_xor(p, off, 64);
        partial = p;
    }
}

extern "C" void kernel_launch(void* const* d_in, const int* in_sizes, int n_in,
                              void* d_out, int out_size, void* d_ws, size_t ws_size,
                              hipStream_t stream) {
    const float* ini    = (const float*)d_in[0];   // initial_spikes [512][100]
    const float* frames = (const float*)d_in[1];   // input_frames  [300][25600]
    const float* sfil   = (const float*)d_in[2];   // spat_filters  [512][25600]
    const float* ff     = (const float*)d_in[3];   // feedback_filters [512][100]
    const float* cf     = (const float*)d_in[4];   // coupling_filters [512][20][100]
    const float* bias   = (const float*)d_in[5];   // [512][1]
    const float* fw     = (const float*)d_in[6];   // forward_weights [1500][2]
    const int*   sel    = (const int*)d_in[7];     // coupled_sel [512][20]
    const int*   fs     = (const int*)d_in[8];     // forward_sel [1500][2]
    float* out = (float*)d_out;
    float* ws  = (float*)d_ws;

    // ws layout (floats):
    //   part  @ 0         (KSPLIT*153600 = 1228800)   dead after reduce
    //   stimb @ 0         (768000)   overlaps dead part
    //   X64   @ 768000    (8192 f-equiv) overlaps dead part, persists through scan
    //   spat  @ 1228800   (153600)
    //   total = 1382400 floats = 5.53 MB (< proven 6.2 MB footprint)
    float* part  = ws;
    float* stimb = ws;
    unsigned long long* X64 = (unsigned long long*)(ws + 768000);
    float* spat  = ws + 1228800;

    hipLaunchKernelGGL(gemm_mfma_k,
                       dim3(KSPLIT, (N_FRAMES + MT - 1) / MT, N_CELLS / NT), dim3(256), 0, stream,
                       frames, sfil, part);
    hipLaunchKernelGGL(reduce_part_k, dim3((N_FRAMES * N_CELLS + 255) / 256), dim3(256), 0, stream, part, spat);
    hipLaunchKernelGGL(prep2_k, dim3((NBT * N_CELLS + 255) / 256), dim3(256), 0, stream,
                       spat, bias, fw, fs, ini, stimb, X64, out);
    hipLaunchKernelGGL(scan_k, dim3(NWG), dim3(SCAN_THREADS), 0, stream,
                       stimb, cf, ff, sel, ini, X64, out);
}